// Round 1
// baseline (1355.840 us; speedup 1.0000x reference)
//
#include <hip/hip_runtime.h>

#define TT 4096
#define BB 1024
#define CH 32
#define NCH 128            // TT/CH
#define TB 4194304         // TT*BB
#define OFF_LOGP (TB)
#define OFF_ENT  (2*TB)
#define OFF_VAL  (3*TB)
#define OFF_HN   (4*TB)
#define OFF_CN   (4*TB + 16384)

__device__ __forceinline__ float fsig(float x){
    return __builtin_amdgcn_rcpf(1.f + __expf(-x));
}
__device__ __forceinline__ float ftanh_(float x){
    return 1.f - 2.f*__builtin_amdgcn_rcpf(1.f + __expf(2.f*x));
}

struct P {
    const float* __restrict__ x;
    const int*   __restrict__ done;
    const int*   __restrict__ action;
    const float* __restrict__ h0;
    const float* __restrict__ c0;
    const float* __restrict__ w1;
    const float* __restrict__ b1;
    const float* __restrict__ w_ih;
    const float* __restrict__ w_hh;
    const float* __restrict__ b_ih;
    const float* __restrict__ b_hh;
    const float* __restrict__ actor_w;
    const float* __restrict__ actor_b;
    const float* __restrict__ critic_w;
    const float* __restrict__ critic_b;
    float* __restrict__ out;
    float* __restrict__ carry;   // [NCH][32][BB] : per chunk, 16 h then 16 c, b-fast
    int*   __restrict__ valid;   // [NCH][BB]
};

// One LSTM step + actor/critic outputs for (t, b). Updates h, c in place.
__device__ __forceinline__ void cell_and_out(const P& p, int t, int b,
                                             float h[16], float c[16])
{
    const float2 xv = *reinterpret_cast<const float2*>(p.x + 2*(t*BB + b));
    float hid[16];
#pragma unroll
    for (int k = 0; k < 16; k++) {
        float v = fmaf(p.w1[2*k], xv.x, fmaf(p.w1[2*k+1], xv.y, p.b1[k]));
        hid[k] = fmaxf(v, 0.f);
    }
    float nh[16], nc[16];
#pragma unroll
    for (int k = 0; k < 16; k++) {
        float ai = p.b_ih[k]      + p.b_hh[k];
        float af = p.b_ih[16+k]   + p.b_hh[16+k];
        float ag = p.b_ih[32+k]   + p.b_hh[32+k];
        float ao = p.b_ih[48+k]   + p.b_hh[48+k];
#pragma unroll
        for (int j = 0; j < 16; j++) {
            float hj = hid[j];
            ai = fmaf(p.w_ih[(k)*16+j],    hj, ai);
            af = fmaf(p.w_ih[(16+k)*16+j], hj, af);
            ag = fmaf(p.w_ih[(32+k)*16+j], hj, ag);
            ao = fmaf(p.w_ih[(48+k)*16+j], hj, ao);
        }
#pragma unroll
        for (int j = 0; j < 16; j++) {
            float hj = h[j];
            ai = fmaf(p.w_hh[(k)*16+j],    hj, ai);
            af = fmaf(p.w_hh[(16+k)*16+j], hj, af);
            ag = fmaf(p.w_hh[(32+k)*16+j], hj, ag);
            ao = fmaf(p.w_hh[(48+k)*16+j], hj, ao);
        }
        float si = fsig(ai), sf = fsig(af), sg = ftanh_(ag), so = fsig(ao);
        float cv = fmaf(sf, c[k], si*sg);
        nc[k] = cv;
        nh[k] = so * ftanh_(cv);
    }
#pragma unroll
    for (int k = 0; k < 16; k++) { h[k] = nh[k]; c[k] = nc[k]; }

    // actor / critic heads
    float l0 = p.actor_b[0], l1 = p.actor_b[1], l2 = p.actor_b[2], l3 = p.actor_b[3];
    float v  = p.critic_b[0];
#pragma unroll
    for (int j = 0; j < 16; j++) {
        float hj = h[j];
        l0 = fmaf(p.actor_w[j],    hj, l0);
        l1 = fmaf(p.actor_w[16+j], hj, l1);
        l2 = fmaf(p.actor_w[32+j], hj, l2);
        l3 = fmaf(p.actor_w[48+j], hj, l3);
        v  = fmaf(p.critic_w[j],   hj, v);
    }
    float mx = fmaxf(fmaxf(l0,l1), fmaxf(l2,l3));
    float e0 = __expf(l0-mx), e1 = __expf(l1-mx), e2 = __expf(l2-mx), e3 = __expf(l3-mx);
    float s  = e0+e1+e2+e3;
    float ls = __logf(s);
    float inv = __builtin_amdgcn_rcpf(s);
    float lp0 = l0-mx-ls, lp1 = l1-mx-ls, lp2 = l2-mx-ls, lp3 = l3-mx-ls;
    int idx = t*BB + b;
    int a = p.action[idx];
    float lp = (a==0) ? lp0 : (a==1) ? lp1 : (a==2) ? lp2 : lp3;
    float ent = -(e0*lp0 + e1*lp1 + e2*lp2 + e3*lp3) * inv;
    p.out[OFF_LOGP + idx] = lp;
    p.out[OFF_ENT  + idx] = ent;
    p.out[OFF_VAL  + idx] = v;
}

// Phase 1: every (b, chunk) from zero-state with done-masking. Outputs exact
// from chunk's first reset onward; carry-out exact iff chunk has a reset.
__global__ __launch_bounds__(256, 2) void k_phase1(P p)
{
    int tid = blockIdx.x*blockDim.x + threadIdx.x;
    int b  = tid & (BB-1);
    int ch = tid >> 10;
    int t0 = ch * CH;
    float h[16], c[16];
#pragma unroll
    for (int k = 0; k < 16; k++) { h[k] = 0.f; c[k] = 0.f; }
    int hasreset = 0;
    for (int s = 0; s < CH; s++) {
        int t = t0 + s;
        int d = p.done[t*BB + b];
        hasreset |= d;
        float m = d ? 0.f : 1.f;
#pragma unroll
        for (int k = 0; k < 16; k++) { h[k] *= m; c[k] *= m; }
        cell_and_out(p, t, b, h, c);
    }
    if (hasreset) {
#pragma unroll
        for (int k = 0; k < 16; k++) {
            p.carry[(ch*32 + k)*BB + b]      = h[k];
            p.carry[(ch*32 + 16 + k)*BB + b] = c[k];
        }
    }
    p.valid[ch*BB + b] = hasreset;
}

// Phase 2: redo the pre-first-reset prefix of each chunk with the true carry.
__global__ __launch_bounds__(256, 2) void k_phase2(P p)
{
    int tid = blockIdx.x*blockDim.x + threadIdx.x;
    int b  = tid & (BB-1);
    int ch = tid >> 10;
    float h[16], c[16];
    if (ch == 0) {
#pragma unroll
        for (int k = 0; k < 16; k++) { h[k] = p.h0[b*16+k]; c[k] = p.c0[b*16+k]; }
    } else {
        if (!p.valid[(ch-1)*BB + b]) return;   // pathological; phase 3 covers
#pragma unroll
        for (int k = 0; k < 16; k++) {
            h[k] = p.carry[((ch-1)*32 + k)*BB + b];
            c[k] = p.carry[((ch-1)*32 + 16 + k)*BB + b];
        }
    }
    int t0 = ch * CH;
    bool full = true;
    for (int s = 0; s < CH; s++) {
        int t = t0 + s;
        if (p.done[t*BB + b]) { full = false; break; }
        cell_and_out(p, t, b, h, c);
    }
    if (ch == NCH-1) {
        if (full) {
#pragma unroll
            for (int k = 0; k < 16; k++) {
                p.out[OFF_HN + b*16 + k] = h[k];
                p.out[OFF_CN + b*16 + k] = c[k];
            }
        } else {
#pragma unroll
            for (int k = 0; k < 16; k++) {
                p.out[OFF_HN + b*16 + k] = p.carry[((NCH-1)*32 + k)*BB + b];
                p.out[OFF_CN + b*16 + k] = p.carry[((NCH-1)*32 + 16 + k)*BB + b];
            }
        }
    }
}

// Phase 3: sequential per-env fixup for chunks with no reset (P ~ 2^-32 each).
__global__ void k_phase3(P p)
{
    int b = blockIdx.x*blockDim.x + threadIdx.x;
    if (b >= BB) return;
    bool anybad = false;
    for (int ch = 0; ch < NCH; ch++) anybad |= (p.valid[ch*BB + b] == 0);
    if (!anybad) return;

    int fixed_until = 0;
    for (int ch = 0; ch < NCH; ch++) {
        if (p.valid[ch*BB + b]) continue;
        int t0 = ch * CH;
        if (t0 < fixed_until) continue;
        float h[16], c[16];
        if (ch == 0) {
#pragma unroll
            for (int k = 0; k < 16; k++) { h[k] = p.h0[b*16+k]; c[k] = p.c0[b*16+k]; }
        } else {
#pragma unroll
            for (int k = 0; k < 16; k++) {
                h[k] = p.carry[((ch-1)*32 + k)*BB + b];
                c[k] = p.carry[((ch-1)*32 + 16 + k)*BB + b];
            }
        }
        int t;
        for (t = t0; t < TT; t++) {
            if (p.done[t*BB + b]) break;
            cell_and_out(p, t, b, h, c);
            if (((t+1) & (CH-1)) == 0) {
                int cc = t >> 5;  // chunk just completed
#pragma unroll
                for (int k = 0; k < 16; k++) {
                    p.carry[(cc*32 + k)*BB + b]      = h[k];
                    p.carry[(cc*32 + 16 + k)*BB + b] = c[k];
                }
                p.valid[cc*BB + b] = 1;
            }
        }
        if (t == TT) {
#pragma unroll
            for (int k = 0; k < 16; k++) {
                p.out[OFF_HN + b*16 + k] = h[k];
                p.out[OFF_CN + b*16 + k] = c[k];
            }
        }
        fixed_until = t;
    }
    // Cover the case where phase 2's last-chunk thread early-returned.
    if (p.valid[(NCH-1)*BB + b]) {
#pragma unroll
        for (int k = 0; k < 16; k++) {
            p.out[OFF_HN + b*16 + k] = p.carry[((NCH-1)*32 + k)*BB + b];
            p.out[OFF_CN + b*16 + k] = p.carry[((NCH-1)*32 + 16 + k)*BB + b];
        }
    }
}

// action passthrough: int -> float, vectorized
__global__ void k_action(const int* __restrict__ action, float* __restrict__ out)
{
    int i = blockIdx.x*blockDim.x + threadIdx.x;
    int4 a = reinterpret_cast<const int4*>(action)[i];
    float4 f = make_float4((float)a.x, (float)a.y, (float)a.z, (float)a.w);
    reinterpret_cast<float4*>(out)[i] = f;
}

extern "C" void kernel_launch(void* const* d_in, const int* in_sizes, int n_in,
                              void* d_out, int out_size, void* d_ws, size_t ws_size,
                              hipStream_t stream)
{
    P p;
    p.x        = (const float*)d_in[0];
    p.done     = (const int*)  d_in[1];
    p.action   = (const int*)  d_in[2];
    p.h0       = (const float*)d_in[3];
    p.c0       = (const float*)d_in[4];
    p.w1       = (const float*)d_in[5];
    p.b1       = (const float*)d_in[6];
    p.w_ih     = (const float*)d_in[7];
    p.w_hh     = (const float*)d_in[8];
    p.b_ih     = (const float*)d_in[9];
    p.b_hh     = (const float*)d_in[10];
    p.actor_w  = (const float*)d_in[11];
    p.actor_b  = (const float*)d_in[12];
    p.critic_w = (const float*)d_in[13];
    p.critic_b = (const float*)d_in[14];
    p.out   = (float*)d_out;
    p.carry = (float*)d_ws;                                      // 16 MiB
    p.valid = (int*)((char*)d_ws + (size_t)NCH*32*BB*sizeof(float));

    hipLaunchKernelGGL(k_action, dim3(TB/4/256), dim3(256), 0, stream, p.action, p.out);
    hipLaunchKernelGGL(k_phase1, dim3(NCH*BB/256), dim3(256), 0, stream, p);
    hipLaunchKernelGGL(k_phase2, dim3(NCH*BB/256), dim3(256), 0, stream, p);
    hipLaunchKernelGGL(k_phase3, dim3(BB/256), dim3(256), 0, stream, p);
}

// Round 2
// 1038.674 us; speedup vs baseline: 1.3054x; 1.3054x over previous
//
#include <hip/hip_runtime.h>

#define TT 4096
#define BB 1024
#define TB 4194304         // TT*BB
#define OFF_LOGP (TB)
#define OFF_ENT  (2*TB)
#define OFF_VAL  (3*TB)
#define OFF_HN   (4*TB)
#define OFF_CN   (4*TB + 16384)

typedef float f32x2 __attribute__((ext_vector_type(2)));

__device__ __forceinline__ float fsig(float x){
    return __builtin_amdgcn_rcpf(1.f + __expf(-x));
}
__device__ __forceinline__ float ftanh_(float x){
    return 1.f - 2.f*__builtin_amdgcn_rcpf(1.f + __expf(2.f*x));
}

// Const-pointer bundle built INSIDE each kernel from top-level __restrict__
// args (noalias provenance survives through the struct copy after inlining).
struct CP {
    const float* x;
    const int*   done;
    const int*   action;
    const float* h0;
    const float* c0;
    const f32x2* w12;     // w1 as 16 rows of one float2 each
    const float* b1;
    const f32x2* wih2;    // [64][8] pairs, row-major
    const f32x2* whh2;    // [64][8]
    const float* bsum;    // b_ih + b_hh, [64]
    const f32x2* aw2;     // actor_w [4][8] pairs
    const float* ab;
    const f32x2* cw2;     // critic_w [8] pairs
    const float* cb;
    float* out;
    float* carry;         // [NC][32][BB]
    int*   valid;         // [NC][BB]
};

#define KPARAMS const float* __restrict__ x, const int* __restrict__ done, \
    const int* __restrict__ action, const float* __restrict__ h0, \
    const float* __restrict__ c0, const float* __restrict__ w1, \
    const float* __restrict__ b1, const float* __restrict__ w_ih, \
    const float* __restrict__ w_hh, const float* __restrict__ bsum, \
    const float* __restrict__ actor_w, const float* __restrict__ actor_b, \
    const float* __restrict__ critic_w, const float* __restrict__ critic_b, \
    float* __restrict__ out, float* __restrict__ carry, int* __restrict__ valid

#define MAKE_CP() CP p; \
    p.x = x; p.done = done; p.action = action; p.h0 = h0; p.c0 = c0; \
    p.w12 = (const f32x2*)w1; p.b1 = b1; \
    p.wih2 = (const f32x2*)w_ih; p.whh2 = (const f32x2*)w_hh; p.bsum = bsum; \
    p.aw2 = (const f32x2*)actor_w; p.ab = actor_b; \
    p.cw2 = (const f32x2*)critic_w; p.cb = critic_b; \
    p.out = out; p.carry = carry; p.valid = valid

// One LSTM step + heads for (t,b). h kept as 8 float2 pairs, c as 16 floats.
__device__ __forceinline__ void cell_and_out(const CP& p, int t, int b,
                                             f32x2 h2[8], float c[16])
{
    const int idx = t*BB + b;
    const f32x2 xv = *(const f32x2*)(p.x + 2*(size_t)idx);

    // MLP encoder: hid = relu(w1 @ x + b1), packed into 8 float2
    f32x2 hid2[8];
#pragma unroll
    for (int k = 0; k < 16; k++) {
        f32x2 pr = p.w12[k] * xv;                    // v_pk_mul_f32
        float hv = fmaxf(pr[0] + pr[1] + p.b1[k], 0.f);
        hid2[k>>1][k&1] = hv;
    }

    float nc[16];
    f32x2 nh2[8];
#pragma unroll
    for (int k = 0; k < 16; k++) {
        f32x2 ai = {0.f,0.f}, af = {0.f,0.f}, ag = {0.f,0.f}, ao = {0.f,0.f};
#pragma unroll
        for (int j = 0; j < 8; j++) {
            f32x2 hj = hid2[j];
            ai = __builtin_elementwise_fma(p.wih2[(k)*8+j],    hj, ai);
            af = __builtin_elementwise_fma(p.wih2[(16+k)*8+j], hj, af);
            ag = __builtin_elementwise_fma(p.wih2[(32+k)*8+j], hj, ag);
            ao = __builtin_elementwise_fma(p.wih2[(48+k)*8+j], hj, ao);
        }
#pragma unroll
        for (int j = 0; j < 8; j++) {
            f32x2 hj = h2[j];
            ai = __builtin_elementwise_fma(p.whh2[(k)*8+j],    hj, ai);
            af = __builtin_elementwise_fma(p.whh2[(16+k)*8+j], hj, af);
            ag = __builtin_elementwise_fma(p.whh2[(32+k)*8+j], hj, ag);
            ao = __builtin_elementwise_fma(p.whh2[(48+k)*8+j], hj, ao);
        }
        float gi = ai[0] + ai[1] + p.bsum[k];
        float gf = af[0] + af[1] + p.bsum[16+k];
        float gg = ag[0] + ag[1] + p.bsum[32+k];
        float go = ao[0] + ao[1] + p.bsum[48+k];
        float si = fsig(gi), sf = fsig(gf), sg = ftanh_(gg), so = fsig(go);
        float cv = fmaf(sf, c[k], si*sg);
        nc[k] = cv;
        nh2[k>>1][k&1] = so * ftanh_(cv);
    }
#pragma unroll
    for (int k = 0; k < 16; k++) c[k] = nc[k];
#pragma unroll
    for (int j = 0; j < 8; j++) h2[j] = nh2[j];

    // actor / critic heads (packed)
    f32x2 a0 = {0.f,0.f}, a1 = {0.f,0.f}, a2 = {0.f,0.f}, a3 = {0.f,0.f}, av = {0.f,0.f};
#pragma unroll
    for (int j = 0; j < 8; j++) {
        f32x2 hj = h2[j];
        a0 = __builtin_elementwise_fma(p.aw2[j],    hj, a0);
        a1 = __builtin_elementwise_fma(p.aw2[8+j],  hj, a1);
        a2 = __builtin_elementwise_fma(p.aw2[16+j], hj, a2);
        a3 = __builtin_elementwise_fma(p.aw2[24+j], hj, a3);
        av = __builtin_elementwise_fma(p.cw2[j],    hj, av);
    }
    float l0 = a0[0]+a0[1]+p.ab[0], l1 = a1[0]+a1[1]+p.ab[1];
    float l2 = a2[0]+a2[1]+p.ab[2], l3 = a3[0]+a3[1]+p.ab[3];
    float v  = av[0]+av[1]+p.cb[0];

    float mx = fmaxf(fmaxf(l0,l1), fmaxf(l2,l3));
    float e0 = __expf(l0-mx), e1 = __expf(l1-mx), e2 = __expf(l2-mx), e3 = __expf(l3-mx);
    float s  = e0+e1+e2+e3;
    float ls = __logf(s);
    float inv = __builtin_amdgcn_rcpf(s);
    float lp0 = l0-mx-ls, lp1 = l1-mx-ls, lp2 = l2-mx-ls, lp3 = l3-mx-ls;
    int a = p.action[idx];
    float lp = (a==0) ? lp0 : (a==1) ? lp1 : (a==2) ? lp2 : lp3;
    float ent = -(e0*lp0 + e1*lp1 + e2*lp2 + e3*lp3) * inv;
    p.out[idx]            = (float)a;    // action passthrough
    p.out[OFF_LOGP + idx] = lp;
    p.out[OFF_ENT  + idx] = ent;
    p.out[OFF_VAL  + idx] = v;
}

// Phase 1: every (b, chunk) from zero state with done-masking.
template<int LCH>
__global__ __launch_bounds__(256, 4) void k_phase1(KPARAMS)
{
    MAKE_CP();
    constexpr int CHS = 1 << LCH;
    int tid = blockIdx.x*256 + threadIdx.x;
    int b  = tid & (BB-1);
    int ch = tid >> 10;
    int t0 = ch << LCH;
    f32x2 h2[8]; float c[16];
#pragma unroll
    for (int j = 0; j < 8; j++) h2[j] = (f32x2){0.f,0.f};
#pragma unroll
    for (int k = 0; k < 16; k++) c[k] = 0.f;
    int hasreset = 0;
    for (int s = 0; s < CHS; s++) {
        int t = t0 + s;
        int d = p.done[t*BB + b];
        hasreset |= d;
        float m = d ? 0.f : 1.f;
#pragma unroll
        for (int j = 0; j < 8; j++) h2[j] = h2[j] * m;
#pragma unroll
        for (int k = 0; k < 16; k++) c[k] *= m;
        cell_and_out(p, t, b, h2, c);
    }
    if (hasreset) {
#pragma unroll
        for (int j = 0; j < 8; j++) {
            p.carry[(ch*32 + 2*j  )*BB + b] = h2[j][0];
            p.carry[(ch*32 + 2*j+1)*BB + b] = h2[j][1];
        }
#pragma unroll
        for (int k = 0; k < 16; k++)
            p.carry[(ch*32 + 16 + k)*BB + b] = c[k];
    }
    p.valid[ch*BB + b] = hasreset;
}

// Phase 2: redo the pre-first-reset prefix of each chunk with the true carry.
template<int LCH>
__global__ __launch_bounds__(256, 4) void k_phase2(KPARAMS)
{
    MAKE_CP();
    constexpr int CHS = 1 << LCH;
    constexpr int NC  = TT >> LCH;
    int tid = blockIdx.x*256 + threadIdx.x;
    int b  = tid & (BB-1);
    int ch = tid >> 10;
    f32x2 h2[8]; float c[16];
    if (ch == 0) {
#pragma unroll
        for (int j = 0; j < 8; j++) h2[j] = ((const f32x2*)p.h0)[b*8+j];
#pragma unroll
        for (int k = 0; k < 16; k++) c[k] = p.c0[b*16+k];
    } else {
        if (!p.valid[(ch-1)*BB + b]) return;   // pathological; phase 3 covers
#pragma unroll
        for (int j = 0; j < 8; j++) {
            h2[j][0] = p.carry[((ch-1)*32 + 2*j  )*BB + b];
            h2[j][1] = p.carry[((ch-1)*32 + 2*j+1)*BB + b];
        }
#pragma unroll
        for (int k = 0; k < 16; k++)
            c[k] = p.carry[((ch-1)*32 + 16 + k)*BB + b];
    }
    int t0 = ch << LCH;
    bool full = true;
    for (int s = 0; s < CHS; s++) {
        int t = t0 + s;
        if (p.done[t*BB + b]) { full = false; break; }
        cell_and_out(p, t, b, h2, c);
    }
    if (ch == NC-1) {
        if (full) {
#pragma unroll
            for (int j = 0; j < 8; j++) {
                p.out[OFF_HN + b*16 + 2*j]   = h2[j][0];
                p.out[OFF_HN + b*16 + 2*j+1] = h2[j][1];
            }
#pragma unroll
            for (int k = 0; k < 16; k++)
                p.out[OFF_CN + b*16 + k] = c[k];
        } else {
#pragma unroll
            for (int k = 0; k < 16; k++) {
                p.out[OFF_HN + b*16 + k] = p.carry[((NC-1)*32 + k)*BB + b];
                p.out[OFF_CN + b*16 + k] = p.carry[((NC-1)*32 + 16 + k)*BB + b];
            }
        }
    }
}

// Phase 3: sequential per-env fixup for chunks with no reset (P ~ 2^-CHS each).
template<int LCH>
__global__ void k_phase3(KPARAMS)
{
    MAKE_CP();
    constexpr int CHS = 1 << LCH;
    constexpr int NC  = TT >> LCH;
    int b = blockIdx.x*blockDim.x + threadIdx.x;
    if (b >= BB) return;
    bool anybad = false;
    for (int ch = 0; ch < NC; ch++) anybad |= (p.valid[ch*BB + b] == 0);
    if (!anybad) return;

    int fixed_until = 0;
    for (int ch = 0; ch < NC; ch++) {
        if (p.valid[ch*BB + b]) continue;
        int t0 = ch << LCH;
        if (t0 < fixed_until) continue;
        f32x2 h2[8]; float c[16];
        if (ch == 0) {
#pragma unroll
            for (int j = 0; j < 8; j++) h2[j] = ((const f32x2*)p.h0)[b*8+j];
#pragma unroll
            for (int k = 0; k < 16; k++) c[k] = p.c0[b*16+k];
        } else {
#pragma unroll
            for (int j = 0; j < 8; j++) {
                h2[j][0] = p.carry[((ch-1)*32 + 2*j  )*BB + b];
                h2[j][1] = p.carry[((ch-1)*32 + 2*j+1)*BB + b];
            }
#pragma unroll
            for (int k = 0; k < 16; k++)
                c[k] = p.carry[((ch-1)*32 + 16 + k)*BB + b];
        }
        int t;
        for (t = t0; t < TT; t++) {
            if (p.done[t*BB + b]) break;
            cell_and_out(p, t, b, h2, c);
            if (((t+1) & (CHS-1)) == 0) {
                int cc = t >> LCH;  // chunk just completed
#pragma unroll
                for (int j = 0; j < 8; j++) {
                    p.carry[(cc*32 + 2*j  )*BB + b] = h2[j][0];
                    p.carry[(cc*32 + 2*j+1)*BB + b] = h2[j][1];
                }
#pragma unroll
                for (int k = 0; k < 16; k++)
                    p.carry[(cc*32 + 16 + k)*BB + b] = c[k];
                p.valid[cc*BB + b] = 1;
            }
        }
        if (t == TT) {
#pragma unroll
            for (int j = 0; j < 8; j++) {
                p.out[OFF_HN + b*16 + 2*j]   = h2[j][0];
                p.out[OFF_HN + b*16 + 2*j+1] = h2[j][1];
            }
#pragma unroll
            for (int k = 0; k < 16; k++)
                p.out[OFF_CN + b*16 + k] = c[k];
        }
        fixed_until = t;
    }
    // Cover the case where phase 2's last-chunk thread early-returned.
    if (p.valid[(NC-1)*BB + b]) {
#pragma unroll
        for (int k = 0; k < 16; k++) {
            p.out[OFF_HN + b*16 + k] = p.carry[((NC-1)*32 + k)*BB + b];
            p.out[OFF_CN + b*16 + k] = p.carry[((NC-1)*32 + 16 + k)*BB + b];
        }
    }
}

// Prep: bsum = b_ih + b_hh
__global__ void k_prep(const float* __restrict__ b_ih, const float* __restrict__ b_hh,
                       float* __restrict__ bsum)
{
    int i = threadIdx.x;
    if (i < 64) bsum[i] = b_ih[i] + b_hh[i];
}

extern "C" void kernel_launch(void* const* d_in, const int* in_sizes, int n_in,
                              void* d_out, int out_size, void* d_ws, size_t ws_size,
                              hipStream_t stream)
{
    const float* x        = (const float*)d_in[0];
    const int*   done     = (const int*)  d_in[1];
    const int*   action   = (const int*)  d_in[2];
    const float* h0       = (const float*)d_in[3];
    const float* c0       = (const float*)d_in[4];
    const float* w1       = (const float*)d_in[5];
    const float* b1       = (const float*)d_in[6];
    const float* w_ih     = (const float*)d_in[7];
    const float* w_hh     = (const float*)d_in[8];
    const float* b_ih     = (const float*)d_in[9];
    const float* b_hh     = (const float*)d_in[10];
    const float* actor_w  = (const float*)d_in[11];
    const float* actor_b  = (const float*)d_in[12];
    const float* critic_w = (const float*)d_in[13];
    const float* critic_b = (const float*)d_in[14];
    float* out = (float*)d_out;

    // ws layout: bsum[64] | carry[NC*32*BB] | valid[NC*BB]
    float* bsum = (float*)d_ws;

    hipLaunchKernelGGL(k_prep, dim3(1), dim3(64), 0, stream, b_ih, b_hh, bsum);

    const size_t need16 = 256 + (size_t)(TT/16)*32*BB*4 + (size_t)(TT/16)*BB*4;

#define LAUNCH(LCH) do { \
        constexpr int NC = TT >> (LCH); \
        float* carry = (float*)((char*)d_ws + 256); \
        int*   valid = (int*)((char*)d_ws + 256 + (size_t)NC*32*BB*4); \
        hipLaunchKernelGGL((k_phase1<LCH>), dim3(NC*BB/256), dim3(256), 0, stream, \
            x,done,action,h0,c0,w1,b1,w_ih,w_hh,bsum,actor_w,actor_b,critic_w,critic_b,out,carry,valid); \
        hipLaunchKernelGGL((k_phase2<LCH>), dim3(NC*BB/256), dim3(256), 0, stream, \
            x,done,action,h0,c0,w1,b1,w_ih,w_hh,bsum,actor_w,actor_b,critic_w,critic_b,out,carry,valid); \
        hipLaunchKernelGGL((k_phase3<LCH>), dim3(BB/256), dim3(256), 0, stream, \
            x,done,action,h0,c0,w1,b1,w_ih,w_hh,bsum,actor_w,actor_b,critic_w,critic_b,out,carry,valid); \
    } while (0)

    if (ws_size >= need16) {
        LAUNCH(4);
    } else {
        LAUNCH(5);
    }
#undef LAUNCH
}

// Round 3
// 179.789 us; speedup vs baseline: 7.5413x; 5.7772x over previous
//
#include <hip/hip_runtime.h>

#define TT 4096
#define BB 1024
#define LCH 5
#define CH 32
#define NC 128             // TT/CH
#define TB 4194304         // TT*BB
#define OFF_LOGP (TB)
#define OFF_ENT  (2*TB)
#define OFF_VAL  (3*TB)
#define OFF_HN   (4*TB)
#define OFF_CN   (4*TB + 16384)

typedef float    f32x2 __attribute__((ext_vector_type(2)));
typedef float    f32x4 __attribute__((ext_vector_type(4)));
typedef _Float16 f16x4 __attribute__((ext_vector_type(4)));

__device__ __forceinline__ float fsig(float x){
    return __builtin_amdgcn_rcpf(1.f + __expf(-x));
}
__device__ __forceinline__ float ftanh_(float x){
    return 1.f - 2.f*__builtin_amdgcn_rcpf(1.f + __expf(2.f*x));
}
__device__ __forceinline__ f16x4 to_h4(f32x4 v){
    f16x4 r;
    r[0]=(_Float16)v[0]; r[1]=(_Float16)v[1]; r[2]=(_Float16)v[2]; r[3]=(_Float16)v[3];
    return r;
}
__device__ __forceinline__ f32x4 mfma16(f16x4 a, f16x4 b, f32x4 c){
    return __builtin_amdgcn_mfma_f32_16x16x16f16(a, b, c, 0, 0, 0);
}
__device__ __forceinline__ float wred(float v){     // reduce over hi-groups
    v += __shfl_xor(v, 16);
    v += __shfl_xor(v, 32);
    return v;
}
__device__ __forceinline__ float dot4(f32x4 a, f32x4 b){
    return fmaf(a[0],b[0], fmaf(a[1],b[1], fmaf(a[2],b[2], a[3]*b[3])));
}

#define KPARAMS const float* __restrict__ x, const int* __restrict__ done, \
    const int* __restrict__ action, const float* __restrict__ h0, \
    const float* __restrict__ c0, const float* __restrict__ w1, \
    const float* __restrict__ b1, const float* __restrict__ w_ih, \
    const float* __restrict__ w_hh, const float* __restrict__ bsum, \
    const float* __restrict__ actor_w, const float* __restrict__ actor_b, \
    const float* __restrict__ critic_w, const float* __restrict__ critic_b, \
    float* __restrict__ out, float* __restrict__ carry, int* __restrict__ valid

#define KARGS x,done,action,h0,c0,w1,b1,w_ih,w_hh,bsum,actor_w,actor_b,critic_w,critic_b,out,carry,valid

// ---- per-wave constant fragments -----------------------------------------
// Wave handles 16 envs (env = lane&15). MFMA computes D[gate-cell, env] =
// W[gate-cell, k] * state[k, env] + bias. A-frag: lane holds W[16*mt+lo][4*hi+s].
// B-frag: lane holds state[cell=4*hi+s][env=lo]. D: lane holds rows 4*hi+r,
// col=lo -> identical to next step's B layout: transpose-free recurrence.
struct Frags {
    f16x4 wih[4], whh[4];
    f32x4 biasC[4];
    f32x4 aw0, aw1, aw2, aw3, cw;
    float ab0, ab1, ab2, ab3, cb0;
    f32x2 w1r[4];
    f32x4 b1r;
};

__device__ __forceinline__ void load_frags(Frags& F, int lo, int hi,
    const float* w1, const float* b1, const float* w_ih, const float* w_hh,
    const float* bsum, const float* actor_w, const float* actor_b,
    const float* critic_w, const float* critic_b)
{
#pragma unroll
    for (int mt = 0; mt < 4; mt++) {
        F.wih[mt]  = to_h4(*(const f32x4*)(w_ih + (16*mt+lo)*16 + 4*hi));
        F.whh[mt]  = to_h4(*(const f32x4*)(w_hh + (16*mt+lo)*16 + 4*hi));
        F.biasC[mt] = *(const f32x4*)(bsum + 16*mt + 4*hi);
    }
    F.aw0 = *(const f32x4*)(actor_w +  0 + 4*hi);
    F.aw1 = *(const f32x4*)(actor_w + 16 + 4*hi);
    F.aw2 = *(const f32x4*)(actor_w + 32 + 4*hi);
    F.aw3 = *(const f32x4*)(actor_w + 48 + 4*hi);
    F.cw  = *(const f32x4*)(critic_w + 4*hi);
    F.ab0 = actor_b[0]; F.ab1 = actor_b[1]; F.ab2 = actor_b[2]; F.ab3 = actor_b[3];
    F.cb0 = critic_b[0];
#pragma unroll
    for (int r = 0; r < 4; r++) {
        F.w1r[r] = *(const f32x2*)(w1 + (4*hi+r)*2);
        F.b1r[r] = b1[4*hi+r];
    }
}

// One step: gates via MFMA, activations, state update, heads, predicated store.
__device__ __forceinline__ void step_mfma(const Frags& F, f32x4& h, f32x4& cc,
    f32x2 xv, int a, int idx, bool do_store, int hi, float* __restrict__ out)
{
    f32x4 hid;
#pragma unroll
    for (int r = 0; r < 4; r++)
        hid[r] = fmaxf(fmaf(F.w1r[r][0], xv[0], fmaf(F.w1r[r][1], xv[1], F.b1r[r])), 0.f);
    f16x4 hidh = to_h4(hid), hh = to_h4(h);
    f32x4 g0 = mfma16(F.wih[0], hidh, F.biasC[0]);
    f32x4 g1 = mfma16(F.wih[1], hidh, F.biasC[1]);
    f32x4 g2 = mfma16(F.wih[2], hidh, F.biasC[2]);
    f32x4 g3 = mfma16(F.wih[3], hidh, F.biasC[3]);
    g0 = mfma16(F.whh[0], hh, g0);
    g1 = mfma16(F.whh[1], hh, g1);
    g2 = mfma16(F.whh[2], hh, g2);
    g3 = mfma16(F.whh[3], hh, g3);
#pragma unroll
    for (int r = 0; r < 4; r++) {
        float si = fsig(g0[r]), sf = fsig(g1[r]);
        float sg = ftanh_(g2[r]), so = fsig(g3[r]);
        float cv = fmaf(sf, cc[r], si*sg);
        cc[r] = cv;
        h[r]  = so * ftanh_(cv);
    }
    // heads (reduce over hi-groups; all lanes end with full sums for env=lo)
    float l0 = wred(dot4(F.aw0, h)) + F.ab0;
    float l1 = wred(dot4(F.aw1, h)) + F.ab1;
    float l2 = wred(dot4(F.aw2, h)) + F.ab2;
    float l3 = wred(dot4(F.aw3, h)) + F.ab3;
    float vv = wred(dot4(F.cw,  h)) + F.cb0;
    float mx = fmaxf(fmaxf(l0,l1), fmaxf(l2,l3));
    float e0 = __expf(l0-mx), e1 = __expf(l1-mx), e2 = __expf(l2-mx), e3 = __expf(l3-mx);
    float s  = e0+e1+e2+e3;
    float ls = __logf(s);
    float inv = __builtin_amdgcn_rcpf(s);
    float lp0 = l0-mx-ls, lp1 = l1-mx-ls, lp2 = l2-mx-ls, lp3 = l3-mx-ls;
    float lp = (a==0) ? lp0 : (a==1) ? lp1 : (a==2) ? lp2 : lp3;
    float ent = -(e0*lp0 + e1*lp1 + e2*lp2 + e3*lp3) * inv;
    if (do_store && hi == 0) {
        out[idx]            = (float)a;
        out[OFF_LOGP + idx] = lp;
        out[OFF_ENT  + idx] = ent;
        out[OFF_VAL  + idx] = vv;
    }
}

// Phase 1: every (env, chunk) from zero state with done-masking.
__global__ __launch_bounds__(256, 3) void k_phase1(KPARAMS)
{
    const int tid  = blockIdx.x*256 + threadIdx.x;
    const int lane = tid & 63;
    const int lo = lane & 15, hi = lane >> 4;
    const int w    = tid >> 6;
    const int ch   = w >> 6;                 // BB/16 = 64 waves per chunk
    const int base = (w & 63) << 4;
    const int b    = base + lo;
    const int t0   = ch << LCH;

    Frags F;
    load_frags(F, lo, hi, w1, b1, w_ih, w_hh, bsum, actor_w, actor_b, critic_w, critic_b);

    f32x4 h = {0.f,0.f,0.f,0.f}, cc = {0.f,0.f,0.f,0.f};
    int hr = 0;

    int   d_cur = done[t0*BB + b];
    f32x2 x_cur = *(const f32x2*)(x + 2*(size_t)(t0*BB + b));
    int   a_cur = action[t0*BB + b];

#pragma unroll 2
    for (int s = 0; s < CH; s++) {
        const int t = t0 + s;
        const int idx = t*BB + b;
        const int   d  = d_cur;
        const f32x2 xv = x_cur;
        const int   a  = a_cur;
        if (s + 1 < CH) {                     // prefetch next step
            d_cur = done[idx + BB];
            x_cur = *(const f32x2*)(x + 2*(size_t)(idx + BB));
            a_cur = action[idx + BB];
        }
        hr |= d;
        const float m = d ? 0.f : 1.f;
        h *= m; cc *= m;
        step_mfma(F, h, cc, xv, a, idx, true, hi, out);
    }
    if (hr) {
#pragma unroll
        for (int r = 0; r < 4; r++) {
            carry[(ch*32 + 4*hi + r)*BB + b]      = h[r];
            carry[(ch*32 + 16 + 4*hi + r)*BB + b] = cc[r];
        }
    }
    if (hi == 0) valid[ch*BB + b] = hr;
}

// Phase 2: redo the pre-first-reset prefix of each chunk with the true carry.
__global__ __launch_bounds__(256, 3) void k_phase2(KPARAMS)
{
    const int tid  = blockIdx.x*256 + threadIdx.x;
    const int lane = tid & 63;
    const int lo = lane & 15, hi = lane >> 4;
    const int w    = tid >> 6;
    const int ch   = w >> 6;
    const int base = (w & 63) << 4;
    const int b    = base + lo;
    const int t0   = ch << LCH;

    Frags F;
    load_frags(F, lo, hi, w1, b1, w_ih, w_hh, bsum, actor_w, actor_b, critic_w, critic_b);

    f32x4 h, cc;
    bool active;
    if (ch == 0) {
        h  = *(const f32x4*)(h0 + b*16 + 4*hi);
        cc = *(const f32x4*)(c0 + b*16 + 4*hi);
        active = true;
    } else {
        active = (valid[(ch-1)*BB + b] != 0);
#pragma unroll
        for (int r = 0; r < 4; r++) {
            h[r]  = carry[((ch-1)*32 + 4*hi + r)*BB + b];
            cc[r] = carry[((ch-1)*32 + 16 + 4*hi + r)*BB + b];
        }
    }

    for (int s = 0; s < CH; s++) {
        if (!__ballot(active)) break;
        const int t = t0 + s;
        const int idx = t*BB + b;
        const int d = done[idx];
        if (d) active = false;                 // phase-1 value is exact from here
        const f32x2 xv = *(const f32x2*)(x + 2*(size_t)idx);
        const int a = action[idx];
        step_mfma(F, h, cc, xv, a, idx, active, hi, out);
    }

    if (ch == NC-1) {
        if (active) {                          // no reset in entire chunk: ours is exact
#pragma unroll
            for (int r = 0; r < 4; r++) {
                out[OFF_HN + b*16 + 4*hi + r] = h[r];
                out[OFF_CN + b*16 + 4*hi + r] = cc[r];
            }
        } else if (valid[(NC-1)*BB + b]) {
#pragma unroll
            for (int r = 0; r < 4; r++) {
                out[OFF_HN + b*16 + 4*hi + r] = carry[((NC-1)*32 + 4*hi + r)*BB + b];
                out[OFF_CN + b*16 + 4*hi + r] = carry[((NC-1)*32 + 16 + 4*hi + r)*BB + b];
            }
        } // else: phase 3 writes
    }
}

// ---- scalar f32 fallback cell (phase 3 only; ~never executes) ------------
__device__ void cell_scalar(const float* x, const int* action,
    const float* w1, const float* b1, const float* w_ih, const float* w_hh,
    const float* bsum, const float* actor_w, const float* actor_b,
    const float* critic_w, const float* critic_b, float* out,
    int t, int b, float h[16], float c[16])
{
    const int idx = t*BB + b;
    float x0 = x[2*(size_t)idx], x1 = x[2*(size_t)idx+1];
    float hid[16];
#pragma unroll
    for (int k = 0; k < 16; k++)
        hid[k] = fmaxf(fmaf(w1[2*k], x0, fmaf(w1[2*k+1], x1, b1[k])), 0.f);
    float nh[16], nc[16];
#pragma unroll
    for (int k = 0; k < 16; k++) {
        float ai = bsum[k], af = bsum[16+k], ag = bsum[32+k], ao = bsum[48+k];
#pragma unroll
        for (int j = 0; j < 16; j++) {
            ai = fmaf(w_ih[k*16+j],      hid[j], ai);
            af = fmaf(w_ih[(16+k)*16+j], hid[j], af);
            ag = fmaf(w_ih[(32+k)*16+j], hid[j], ag);
            ao = fmaf(w_ih[(48+k)*16+j], hid[j], ao);
        }
#pragma unroll
        for (int j = 0; j < 16; j++) {
            ai = fmaf(w_hh[k*16+j],      h[j], ai);
            af = fmaf(w_hh[(16+k)*16+j], h[j], af);
            ag = fmaf(w_hh[(32+k)*16+j], h[j], ag);
            ao = fmaf(w_hh[(48+k)*16+j], h[j], ao);
        }
        float si = fsig(ai), sf = fsig(af), sg = ftanh_(ag), so = fsig(ao);
        float cv = fmaf(sf, c[k], si*sg);
        nc[k] = cv; nh[k] = so*ftanh_(cv);
    }
#pragma unroll
    for (int k = 0; k < 16; k++) { h[k] = nh[k]; c[k] = nc[k]; }
    float l0=actor_b[0], l1=actor_b[1], l2=actor_b[2], l3=actor_b[3], v=critic_b[0];
#pragma unroll
    for (int j = 0; j < 16; j++) {
        l0 = fmaf(actor_w[j],    h[j], l0);
        l1 = fmaf(actor_w[16+j], h[j], l1);
        l2 = fmaf(actor_w[32+j], h[j], l2);
        l3 = fmaf(actor_w[48+j], h[j], l3);
        v  = fmaf(critic_w[j],   h[j], v);
    }
    float mx = fmaxf(fmaxf(l0,l1), fmaxf(l2,l3));
    float e0=__expf(l0-mx), e1=__expf(l1-mx), e2=__expf(l2-mx), e3=__expf(l3-mx);
    float s = e0+e1+e2+e3, ls = __logf(s), inv = __builtin_amdgcn_rcpf(s);
    float lp0=l0-mx-ls, lp1=l1-mx-ls, lp2=l2-mx-ls, lp3=l3-mx-ls;
    int a = action[idx];
    float lp = (a==0)?lp0:(a==1)?lp1:(a==2)?lp2:lp3;
    out[idx]            = (float)a;
    out[OFF_LOGP + idx] = lp;
    out[OFF_ENT  + idx] = -(e0*lp0+e1*lp1+e2*lp2+e3*lp3)*inv;
    out[OFF_VAL  + idx] = v;
}

// Phase 3: sequential per-env fixup for chunks with no reset (P ~ 2^-32 each).
__global__ void k_phase3(KPARAMS)
{
    int b = blockIdx.x*blockDim.x + threadIdx.x;
    if (b >= BB) return;
    bool anybad = false;
    for (int ch = 0; ch < NC; ch++) anybad |= (valid[ch*BB + b] == 0);
    if (!anybad) return;

    int fixed_until = 0;
    for (int ch = 0; ch < NC; ch++) {
        if (valid[ch*BB + b]) continue;
        int t0 = ch << LCH;
        if (t0 < fixed_until) continue;
        float h[16], c[16];
        if (ch == 0) {
#pragma unroll
            for (int k = 0; k < 16; k++) { h[k] = h0[b*16+k]; c[k] = c0[b*16+k]; }
        } else {
#pragma unroll
            for (int k = 0; k < 16; k++) {
                h[k] = carry[((ch-1)*32 + k)*BB + b];
                c[k] = carry[((ch-1)*32 + 16 + k)*BB + b];
            }
        }
        int t;
        for (t = t0; t < TT; t++) {
            if (done[t*BB + b]) break;
            cell_scalar(x, action, w1, b1, w_ih, w_hh, bsum,
                        actor_w, actor_b, critic_w, critic_b, out, t, b, h, c);
            if (((t+1) & (CH-1)) == 0) {
                int cc2 = t >> LCH;
#pragma unroll
                for (int k = 0; k < 16; k++) {
                    carry[(cc2*32 + k)*BB + b]      = h[k];
                    carry[(cc2*32 + 16 + k)*BB + b] = c[k];
                }
                valid[cc2*BB + b] = 1;
            }
        }
        if (t == TT) {
#pragma unroll
            for (int k = 0; k < 16; k++) {
                out[OFF_HN + b*16 + k] = h[k];
                out[OFF_CN + b*16 + k] = c[k];
            }
        }
        fixed_until = t;
    }
    if (valid[(NC-1)*BB + b]) {
#pragma unroll
        for (int k = 0; k < 16; k++) {
            out[OFF_HN + b*16 + k] = carry[((NC-1)*32 + k)*BB + b];
            out[OFF_CN + b*16 + k] = carry[((NC-1)*32 + 16 + k)*BB + b];
        }
    }
}

__global__ void k_prep(const float* __restrict__ b_ih, const float* __restrict__ b_hh,
                       float* __restrict__ bsum)
{
    int i = threadIdx.x;
    if (i < 64) bsum[i] = b_ih[i] + b_hh[i];
}

extern "C" void kernel_launch(void* const* d_in, const int* in_sizes, int n_in,
                              void* d_out, int out_size, void* d_ws, size_t ws_size,
                              hipStream_t stream)
{
    const float* x        = (const float*)d_in[0];
    const int*   done     = (const int*)  d_in[1];
    const int*   action   = (const int*)  d_in[2];
    const float* h0       = (const float*)d_in[3];
    const float* c0       = (const float*)d_in[4];
    const float* w1       = (const float*)d_in[5];
    const float* b1       = (const float*)d_in[6];
    const float* w_ih     = (const float*)d_in[7];
    const float* w_hh     = (const float*)d_in[8];
    const float* b_ih     = (const float*)d_in[9];
    const float* b_hh     = (const float*)d_in[10];
    const float* actor_w  = (const float*)d_in[11];
    const float* actor_b  = (const float*)d_in[12];
    const float* critic_w = (const float*)d_in[13];
    const float* critic_b = (const float*)d_in[14];
    float* out = (float*)d_out;

    float* bsum  = (float*)d_ws;
    float* carry = (float*)((char*)d_ws + 256);
    int*   valid = (int*)((char*)d_ws + 256 + (size_t)NC*32*BB*4);

    hipLaunchKernelGGL(k_prep, dim3(1), dim3(64), 0, stream, b_ih, b_hh, bsum);

    const int nthreads = NC*(BB/16)*64;            // one wave per 16 envs
    hipLaunchKernelGGL(k_phase1, dim3(nthreads/256), dim3(256), 0, stream, KARGS);
    hipLaunchKernelGGL(k_phase2, dim3(nthreads/256), dim3(256), 0, stream, KARGS);
    hipLaunchKernelGGL(k_phase3, dim3(BB/256), dim3(256), 0, stream, KARGS);
}

// Round 4
// 164.486 us; speedup vs baseline: 8.2429x; 1.0930x over previous
//
#include <hip/hip_runtime.h>

#define TT 4096
#define BB 1024
#define LCH 5
#define CH 32
#define NC 128             // TT/CH
#define TB 4194304         // TT*BB
#define OFF_LOGP (TB)
#define OFF_ENT  (2*TB)
#define OFF_VAL  (3*TB)
#define OFF_HN   (4*TB)
#define OFF_CN   (4*TB + 16384)

typedef float    f32x2 __attribute__((ext_vector_type(2)));
typedef float    f32x4 __attribute__((ext_vector_type(4)));
typedef _Float16 f16x4 __attribute__((ext_vector_type(4)));

__device__ __forceinline__ float fsig(float x){
    return __builtin_amdgcn_rcpf(1.f + __expf(-x));
}
__device__ __forceinline__ float ftanh_(float x){
    return 1.f - 2.f*__builtin_amdgcn_rcpf(1.f + __expf(2.f*x));
}
__device__ __forceinline__ f16x4 to_h4(f32x4 v){
    f16x4 r;
    r[0]=(_Float16)v[0]; r[1]=(_Float16)v[1]; r[2]=(_Float16)v[2]; r[3]=(_Float16)v[3];
    return r;
}
__device__ __forceinline__ f32x4 from_h4(f16x4 v){
    f32x4 r;
    r[0]=(float)v[0]; r[1]=(float)v[1]; r[2]=(float)v[2]; r[3]=(float)v[3];
    return r;
}
__device__ __forceinline__ f32x4 mfma16(f16x4 a, f16x4 b, f32x4 c){
    return __builtin_amdgcn_mfma_f32_16x16x16f16(a, b, c, 0, 0, 0);
}

#define KPARAMS const float* __restrict__ x, const int* __restrict__ done, \
    const int* __restrict__ action, const float* __restrict__ h0, \
    const float* __restrict__ c0, const float* __restrict__ w1, \
    const float* __restrict__ b1, const float* __restrict__ w_ih, \
    const float* __restrict__ w_hh, const float* __restrict__ bsum, \
    const float* __restrict__ hw16, \
    const float* __restrict__ actor_w, const float* __restrict__ actor_b, \
    const float* __restrict__ critic_w, const float* __restrict__ critic_b, \
    float* __restrict__ out, float* __restrict__ carry, int* __restrict__ valid

#define KARGS x,done,action,h0,c0,w1,b1,w_ih,w_hh,bsum,hw16,actor_w,actor_b,critic_w,critic_b,out,carry,valid

// ---- per-wave constant fragments -----------------------------------------
// Wave handles 16 envs (env = lane&15 = lo). Verified gate mapping:
//   A[row=lo][k=4*hi+s], B[k=4*hi+s][col=lo], C/D[row=4*hi+r][col=lo].
// Head MFMA reuses it: HW rows 0-3 = actor_w, row 4 = critic_w, rest 0 ->
// hi==0 lanes get l0..l3 in regs 0..3; hi==1 lane reg 0 = value.
struct Frags {
    f16x4 wih[4], whh[4], hw;
    f32x4 biasC[4], biasH;
    f32x2 w1r[4];
    f32x4 b1r;
};

__device__ __forceinline__ void load_frags(Frags& F, int lo, int hi,
    const float* w1, const float* b1, const float* w_ih, const float* w_hh,
    const float* bsum, const float* hw16, const float* actor_b,
    const float* critic_b)
{
#pragma unroll
    for (int mt = 0; mt < 4; mt++) {
        F.wih[mt]   = to_h4(*(const f32x4*)(w_ih + (16*mt+lo)*16 + 4*hi));
        F.whh[mt]   = to_h4(*(const f32x4*)(w_hh + (16*mt+lo)*16 + 4*hi));
        F.biasC[mt] = *(const f32x4*)(bsum + 16*mt + 4*hi);
    }
    F.hw = to_h4(*(const f32x4*)(hw16 + lo*16 + 4*hi));
    if (hi == 0)       F.biasH = *(const f32x4*)(actor_b);
    else if (hi == 1)  F.biasH = (f32x4){critic_b[0], 0.f, 0.f, 0.f};
    else               F.biasH = (f32x4){0.f, 0.f, 0.f, 0.f};
#pragma unroll
    for (int r = 0; r < 4; r++) {
        F.w1r[r] = *(const f32x2*)(w1 + (4*hi+r)*2);
        F.b1r[r] = b1[4*hi+r];
    }
}

// One step: gates via MFMA, activations, head MFMA, predicated stores.
// State: hh (f16), cc (f32).
__device__ __forceinline__ void step_mfma(const Frags& F, f16x4& hh, f32x4& cc,
    f32x2 xv, int a, int idx, bool do_store, int hi, float* __restrict__ out)
{
    f32x4 hid;
#pragma unroll
    for (int r = 0; r < 4; r++)
        hid[r] = fmaxf(fmaf(F.w1r[r][0], xv[0], fmaf(F.w1r[r][1], xv[1], F.b1r[r])), 0.f);
    f16x4 hidh = to_h4(hid);
    f32x4 g0 = mfma16(F.whh[0], hh, F.biasC[0]);
    f32x4 g1 = mfma16(F.whh[1], hh, F.biasC[1]);
    f32x4 g2 = mfma16(F.whh[2], hh, F.biasC[2]);
    f32x4 g3 = mfma16(F.whh[3], hh, F.biasC[3]);
    g0 = mfma16(F.wih[0], hidh, g0);
    g1 = mfma16(F.wih[1], hidh, g1);
    g2 = mfma16(F.wih[2], hidh, g2);
    g3 = mfma16(F.wih[3], hidh, g3);
    f32x4 hn;
#pragma unroll
    for (int r = 0; r < 4; r++) {
        float si = fsig(g0[r]), sf = fsig(g1[r]);
        float sg = ftanh_(g2[r]), so = fsig(g3[r]);
        float cv = fmaf(sf, cc[r], si*sg);
        cc[r] = cv;
        hn[r] = so * ftanh_(cv);
    }
    hh = to_h4(hn);
    f32x4 dh = mfma16(F.hw, hh, F.biasH);
    if (do_store) {
        if (hi == 0) {
            // softmax over dh[0..3]; |logits| ~< 0.2 by construction -> no max-sub
            float e0 = __expf(dh[0]), e1 = __expf(dh[1]);
            float e2 = __expf(dh[2]), e3 = __expf(dh[3]);
            float s  = e0+e1+e2+e3;
            float ls = __logf(s);
            float t  = e0*dh[0] + e1*dh[1] + e2*dh[2] + e3*dh[3];
            float ent = ls - t*__builtin_amdgcn_rcpf(s);
            float lsel = (a==0) ? dh[0] : (a==1) ? dh[1] : (a==2) ? dh[2] : dh[3];
            out[idx]            = (float)a;
            out[OFF_LOGP + idx] = lsel - ls;
            out[OFF_ENT  + idx] = ent;
        } else if (hi == 1) {
            out[OFF_VAL + idx] = dh[0];
        }
    }
}

// Phase 1: every (env, chunk) from zero state with done-masking.
__global__ __launch_bounds__(256, 4) void k_phase1(KPARAMS)
{
    const int tid  = blockIdx.x*256 + threadIdx.x;
    const int lane = tid & 63;
    const int lo = lane & 15, hi = lane >> 4;
    const int w    = tid >> 6;
    const int ch   = w >> 6;                 // BB/16 = 64 waves per chunk
    const int base = (w & 63) << 4;
    const int b    = base + lo;
    const int t0   = ch << LCH;

    Frags F;
    load_frags(F, lo, hi, w1, b1, w_ih, w_hh, bsum, hw16, actor_b, critic_b);

    f16x4 hh = {(_Float16)0.f,(_Float16)0.f,(_Float16)0.f,(_Float16)0.f};
    f32x4 cc = {0.f,0.f,0.f,0.f};
    int hr = 0;

    int   d_cur = done[t0*BB + b];
    f32x2 x_cur = *(const f32x2*)(x + 2*(size_t)(t0*BB + b));
    int   a_cur = action[t0*BB + b];

#pragma unroll 2
    for (int s = 0; s < CH; s++) {
        const int idx = (t0 + s)*BB + b;
        const int   d  = d_cur;
        const f32x2 xv = x_cur;
        const int   a  = a_cur;
        if (s + 1 < CH) {                     // prefetch next step
            d_cur = done[idx + BB];
            x_cur = *(const f32x2*)(x + 2*(size_t)(idx + BB));
            a_cur = action[idx + BB];
        }
        hr |= d;
        if (d) {
            hh = (f16x4){(_Float16)0.f,(_Float16)0.f,(_Float16)0.f,(_Float16)0.f};
            cc = (f32x4){0.f,0.f,0.f,0.f};
        }
        step_mfma(F, hh, cc, xv, a, idx, true, hi, out);
    }
    if (hr) {
        f32x4 hf = from_h4(hh);
#pragma unroll
        for (int r = 0; r < 4; r++) {
            carry[(ch*32 + 4*hi + r)*BB + b]      = hf[r];
            carry[(ch*32 + 16 + 4*hi + r)*BB + b] = cc[r];
        }
    }
    if (hi == 0) valid[ch*BB + b] = hr;
}

// Phase 2: redo the pre-first-reset prefix of each chunk with the true carry.
__global__ __launch_bounds__(256, 4) void k_phase2(KPARAMS)
{
    const int tid  = blockIdx.x*256 + threadIdx.x;
    const int lane = tid & 63;
    const int lo = lane & 15, hi = lane >> 4;
    const int w    = tid >> 6;
    const int ch   = w >> 6;
    const int base = (w & 63) << 4;
    const int b    = base + lo;
    const int t0   = ch << LCH;

    Frags F;
    load_frags(F, lo, hi, w1, b1, w_ih, w_hh, bsum, hw16, actor_b, critic_b);

    f32x4 hf, cc;
    bool active;
    if (ch == 0) {
        hf = *(const f32x4*)(h0 + b*16 + 4*hi);
        cc = *(const f32x4*)(c0 + b*16 + 4*hi);
        active = true;
    } else {
        active = (valid[(ch-1)*BB + b] != 0);
#pragma unroll
        for (int r = 0; r < 4; r++) {
            hf[r] = carry[((ch-1)*32 + 4*hi + r)*BB + b];
            cc[r] = carry[((ch-1)*32 + 16 + 4*hi + r)*BB + b];
        }
    }
    f16x4 hh = to_h4(hf);

    for (int s = 0; s < CH; s++) {
        if (!__ballot(active)) break;
        const int idx = (t0 + s)*BB + b;
        const int d = done[idx];
        if (d) active = false;                 // phase-1 value exact from here
        const f32x2 xv = *(const f32x2*)(x + 2*(size_t)idx);
        const int a = action[idx];
        step_mfma(F, hh, cc, xv, a, idx, active, hi, out);
    }

    if (ch == NC-1) {
        if (active) {                          // no reset in entire chunk
            f32x4 ho = from_h4(hh);
#pragma unroll
            for (int r = 0; r < 4; r++) {
                out[OFF_HN + b*16 + 4*hi + r] = ho[r];
                out[OFF_CN + b*16 + 4*hi + r] = cc[r];
            }
        } else if (valid[(NC-1)*BB + b]) {
#pragma unroll
            for (int r = 0; r < 4; r++) {
                out[OFF_HN + b*16 + 4*hi + r] = carry[((NC-1)*32 + 4*hi + r)*BB + b];
                out[OFF_CN + b*16 + 4*hi + r] = carry[((NC-1)*32 + 16 + 4*hi + r)*BB + b];
            }
        } // else: phase 3 writes
    }
}

// ---- scalar f32 fallback cell (phase 3 only; ~never executes) ------------
__device__ void cell_scalar(const float* x, const int* action,
    const float* w1, const float* b1, const float* w_ih, const float* w_hh,
    const float* bsum, const float* actor_w, const float* actor_b,
    const float* critic_w, const float* critic_b, float* out,
    int t, int b, float h[16], float c[16])
{
    const int idx = t*BB + b;
    float x0 = x[2*(size_t)idx], x1 = x[2*(size_t)idx+1];
    float hid[16];
#pragma unroll
    for (int k = 0; k < 16; k++)
        hid[k] = fmaxf(fmaf(w1[2*k], x0, fmaf(w1[2*k+1], x1, b1[k])), 0.f);
    float nh[16], nc[16];
#pragma unroll
    for (int k = 0; k < 16; k++) {
        float ai = bsum[k], af = bsum[16+k], ag = bsum[32+k], ao = bsum[48+k];
#pragma unroll
        for (int j = 0; j < 16; j++) {
            ai = fmaf(w_ih[k*16+j],      hid[j], ai);
            af = fmaf(w_ih[(16+k)*16+j], hid[j], af);
            ag = fmaf(w_ih[(32+k)*16+j], hid[j], ag);
            ao = fmaf(w_ih[(48+k)*16+j], hid[j], ao);
        }
#pragma unroll
        for (int j = 0; j < 16; j++) {
            ai = fmaf(w_hh[k*16+j],      h[j], ai);
            af = fmaf(w_hh[(16+k)*16+j], h[j], af);
            ag = fmaf(w_hh[(32+k)*16+j], h[j], ag);
            ao = fmaf(w_hh[(48+k)*16+j], h[j], ao);
        }
        float si = fsig(ai), sf = fsig(af), sg = ftanh_(ag), so = fsig(ao);
        float cv = fmaf(sf, c[k], si*sg);
        nc[k] = cv; nh[k] = so*ftanh_(cv);
    }
#pragma unroll
    for (int k = 0; k < 16; k++) { h[k] = nh[k]; c[k] = nc[k]; }
    float l0=actor_b[0], l1=actor_b[1], l2=actor_b[2], l3=actor_b[3], v=critic_b[0];
#pragma unroll
    for (int j = 0; j < 16; j++) {
        l0 = fmaf(actor_w[j],    h[j], l0);
        l1 = fmaf(actor_w[16+j], h[j], l1);
        l2 = fmaf(actor_w[32+j], h[j], l2);
        l3 = fmaf(actor_w[48+j], h[j], l3);
        v  = fmaf(critic_w[j],   h[j], v);
    }
    float mx = fmaxf(fmaxf(l0,l1), fmaxf(l2,l3));
    float e0=__expf(l0-mx), e1=__expf(l1-mx), e2=__expf(l2-mx), e3=__expf(l3-mx);
    float s = e0+e1+e2+e3, ls = __logf(s), inv = __builtin_amdgcn_rcpf(s);
    float lp0=l0-mx-ls, lp1=l1-mx-ls, lp2=l2-mx-ls, lp3=l3-mx-ls;
    int a = action[idx];
    float lp = (a==0)?lp0:(a==1)?lp1:(a==2)?lp2:lp3;
    out[idx]            = (float)a;
    out[OFF_LOGP + idx] = lp;
    out[OFF_ENT  + idx] = -(e0*lp0+e1*lp1+e2*lp2+e3*lp3)*inv;
    out[OFF_VAL  + idx] = v;
}

// Phase 3: sequential per-env fixup for chunks with no reset (P ~ 2^-32 each).
__global__ void k_phase3(KPARAMS)
{
    int b = blockIdx.x*blockDim.x + threadIdx.x;
    if (b >= BB) return;
    bool anybad = false;
    for (int ch = 0; ch < NC; ch++) anybad |= (valid[ch*BB + b] == 0);
    if (!anybad) return;

    int fixed_until = 0;
    for (int ch = 0; ch < NC; ch++) {
        if (valid[ch*BB + b]) continue;
        int t0 = ch << LCH;
        if (t0 < fixed_until) continue;
        float h[16], c[16];
        if (ch == 0) {
#pragma unroll
            for (int k = 0; k < 16; k++) { h[k] = h0[b*16+k]; c[k] = c0[b*16+k]; }
        } else {
#pragma unroll
            for (int k = 0; k < 16; k++) {
                h[k] = carry[((ch-1)*32 + k)*BB + b];
                c[k] = carry[((ch-1)*32 + 16 + k)*BB + b];
            }
        }
        int t;
        for (t = t0; t < TT; t++) {
            if (done[t*BB + b]) break;
            cell_scalar(x, action, w1, b1, w_ih, w_hh, bsum,
                        actor_w, actor_b, critic_w, critic_b, out, t, b, h, c);
            if (((t+1) & (CH-1)) == 0) {
                int cc2 = t >> LCH;
#pragma unroll
                for (int k = 0; k < 16; k++) {
                    carry[(cc2*32 + k)*BB + b]      = h[k];
                    carry[(cc2*32 + 16 + k)*BB + b] = c[k];
                }
                valid[cc2*BB + b] = 1;
            }
        }
        if (t == TT) {
#pragma unroll
            for (int k = 0; k < 16; k++) {
                out[OFF_HN + b*16 + k] = h[k];
                out[OFF_CN + b*16 + k] = c[k];
            }
        }
        fixed_until = t;
    }
    if (valid[(NC-1)*BB + b]) {
#pragma unroll
        for (int k = 0; k < 16; k++) {
            out[OFF_HN + b*16 + k] = carry[((NC-1)*32 + k)*BB + b];
            out[OFF_CN + b*16 + k] = carry[((NC-1)*32 + 16 + k)*BB + b];
        }
    }
}

// Prep: bsum = b_ih + b_hh; hw16 = [actor_w; critic_w; zeros] padded to 16x16
__global__ void k_prep(const float* __restrict__ b_ih, const float* __restrict__ b_hh,
                       const float* __restrict__ actor_w, const float* __restrict__ critic_w,
                       float* __restrict__ bsum, float* __restrict__ hw16)
{
    int i = threadIdx.x;
    if (i < 64) bsum[i] = b_ih[i] + b_hh[i];
    int row = i >> 4, k = i & 15;
    float v = 0.f;
    if (row < 4)        v = actor_w[row*16 + k];
    else if (row == 4)  v = critic_w[k];
    hw16[i] = v;
}

extern "C" void kernel_launch(void* const* d_in, const int* in_sizes, int n_in,
                              void* d_out, int out_size, void* d_ws, size_t ws_size,
                              hipStream_t stream)
{
    const float* x        = (const float*)d_in[0];
    const int*   done     = (const int*)  d_in[1];
    const int*   action   = (const int*)  d_in[2];
    const float* h0       = (const float*)d_in[3];
    const float* c0       = (const float*)d_in[4];
    const float* w1       = (const float*)d_in[5];
    const float* b1       = (const float*)d_in[6];
    const float* w_ih     = (const float*)d_in[7];
    const float* w_hh     = (const float*)d_in[8];
    const float* b_ih     = (const float*)d_in[9];
    const float* b_hh     = (const float*)d_in[10];
    const float* actor_w  = (const float*)d_in[11];
    const float* actor_b  = (const float*)d_in[12];
    const float* critic_w = (const float*)d_in[13];
    const float* critic_b = (const float*)d_in[14];
    float* out = (float*)d_out;

    // ws: bsum[64] @0 | hw16[256] @256B | carry @2048B | valid after carry
    float* bsum  = (float*)d_ws;
    float* hw16  = (float*)((char*)d_ws + 256);
    float* carry = (float*)((char*)d_ws + 2048);
    int*   valid = (int*)((char*)d_ws + 2048 + (size_t)NC*32*BB*4);

    hipLaunchKernelGGL(k_prep, dim3(1), dim3(256), 0, stream,
                       b_ih, b_hh, actor_w, critic_w, bsum, hw16);

    const int nthreads = NC*(BB/16)*64;            // one wave per 16 envs
    hipLaunchKernelGGL(k_phase1, dim3(nthreads/256), dim3(256), 0, stream, KARGS);
    hipLaunchKernelGGL(k_phase2, dim3(nthreads/256), dim3(256), 0, stream, KARGS);
    hipLaunchKernelGGL(k_phase3, dim3(BB/256), dim3(256), 0, stream, KARGS);
}